// Round 15
// baseline (1704.662 us; speedup 1.0000x reference)
//
#include <hip/hip_runtime.h>
#include <cstddef>

#define DM    1024
#define TSEQ  1024
#define NB    2
#define NHEAD 16
#define HDIM  64
#define NLAYER 8
#define DFFN  4096
#define NVOC  32000
#define NROWS (NB*TSEQ)

typedef __attribute__((ext_vector_type(8))) short short8;
typedef __attribute__((ext_vector_type(4))) float f32x4;

static __device__ __forceinline__ unsigned short f2bf(float f) {
    union { float f; unsigned int u; } v; v.f = f;
    unsigned int r = v.u + 0x7FFF + ((v.u >> 16) & 1);   // RNE
    return (unsigned short)(r >> 16);
}

static __device__ __forceinline__ void gload_lds16(const void* g, void* l) {
    __builtin_amdgcn_global_load_lds(
        (const __attribute__((address_space(1))) unsigned int*)g,
        (__attribute__((address_space(3))) unsigned int*)l, 16, 0, 0);
}

// ---------------- embedding + positional encoding (f32 out) ----------------
__global__ __launch_bounds__(256)
void embed_pos_k(const int* __restrict__ idx, const float* __restrict__ embed,
                 float* __restrict__ x)
{
    int row = blockIdx.x;
    int t   = row & (TSEQ - 1);
    int tid = threadIdx.x;
    int token = idx[row];
    const float* er = embed + (size_t)token * DM;
    float* xr = x + (size_t)row * DM;
    const float neg_ln1e4_over_d = -9.210340371976184f / (float)DM;
    for (int i = tid; i < DM; i += 256) {
        int half = i >> 1;
        float div = expf((float)(2 * half) * neg_ln1e4_over_d);
        float ang = (float)t * div;
        float pe = (i & 1) ? cosf(ang) : sinf(ang);
        xr[i] = er[i] + pe;
    }
}

// ---------------- layernorm (f32 in, bf16 out) ----------------
__global__ __launch_bounds__(256)
void layernorm_k(const float* __restrict__ x, const float* __restrict__ g,
                 const float* __restrict__ b, unsigned short* __restrict__ y)
{
    int row = blockIdx.x;
    int tid = threadIdx.x;
    const float* xr = x + (size_t)row * DM;
    unsigned short* yr = y + (size_t)row * DM;
    float vals[4];
    float s = 0.f;
    #pragma unroll
    for (int i = 0; i < 4; ++i) { vals[i] = xr[tid + 256 * i]; s += vals[i]; }
    __shared__ float red[256];
    red[tid] = s; __syncthreads();
    for (int st = 128; st > 0; st >>= 1) {
        if (tid < st) red[tid] += red[tid + st];
        __syncthreads();
    }
    float mu = red[0] * (1.f / DM);
    __syncthreads();
    float v = 0.f;
    #pragma unroll
    for (int i = 0; i < 4; ++i) { float d = vals[i] - mu; v += d * d; }
    red[tid] = v; __syncthreads();
    for (int st = 128; st > 0; st >>= 1) {
        if (tid < st) red[tid] += red[tid + st];
        __syncthreads();
    }
    float rstd = rsqrtf(red[0] * (1.f / DM) + 1e-5f);
    #pragma unroll
    for (int i = 0; i < 4; ++i) {
        int c = tid + 256 * i;
        yr[c] = f2bf((vals[i] - mu) * rstd * g[c] + b[c]);
    }
}

// ---------------- fused split-K reduce + residual + bias + layernorm ----------------
__global__ __launch_bounds__(256)
void reduce_ln_k(const float* __restrict__ P, int nsplit, const float* __restrict__ bias,
                 float* __restrict__ X, const float* __restrict__ g,
                 const float* __restrict__ b, unsigned short* __restrict__ XN)
{
    const int row = blockIdx.x;
    const int tid = threadIdx.x;
    const size_t off4 = (size_t)row * 256 + tid;
    const size_t tot4 = (size_t)NROWS * 256;

    float4 v = *((const float4*)X + off4);
    float4 bb = *((const float4*)bias + tid);
    v.x += bb.x; v.y += bb.y; v.z += bb.z; v.w += bb.w;
    for (int s = 0; s < nsplit; ++s) {
        float4 p = *((const float4*)P + s * tot4 + off4);
        v.x += p.x; v.y += p.y; v.z += p.z; v.w += p.w;
    }
    *((float4*)X + off4) = v;

    __shared__ float red[256];
    red[tid] = v.x + v.y + v.z + v.w;
    __syncthreads();
    for (int st = 128; st > 0; st >>= 1) {
        if (tid < st) red[tid] += red[tid + st];
        __syncthreads();
    }
    float mu = red[0] * (1.f / DM);
    __syncthreads();
    float4 d = make_float4(v.x - mu, v.y - mu, v.z - mu, v.w - mu);
    red[tid] = d.x * d.x + d.y * d.y + d.z * d.z + d.w * d.w;
    __syncthreads();
    for (int st = 128; st > 0; st >>= 1) {
        if (tid < st) red[tid] += red[tid + st];
        __syncthreads();
    }
    float rstd = rsqrtf(red[0] * (1.f / DM) + 1e-5f);
    float4 gg = *((const float4*)g + tid);
    float4 bbn = *((const float4*)b + tid);
    unsigned short o[4];
    o[0] = f2bf(d.x * rstd * gg.x + bbn.x);
    o[1] = f2bf(d.y * rstd * gg.y + bbn.y);
    o[2] = f2bf(d.z * rstd * gg.z + bbn.z);
    o[3] = f2bf(d.w * rstd * gg.w + bbn.w);
    *(ushort4*)(XN + (size_t)row * DM + tid * 4) = *(ushort4*)o;
}

// ---------------- weight convert+transpose: f32 [K][N] -> bf16 [N][K] ----------------
__global__ __launch_bounds__(256)
void convt_k(const float* __restrict__ src, unsigned short* __restrict__ dst,
             int K, int N)
{
    __shared__ __align__(16) unsigned short T[64][72];
    const int tid = threadIdx.x;
    const int n0 = blockIdx.x * 64, k0 = blockIdx.y * 64;
    const float* s = src + (size_t)blockIdx.z * K * N;
    unsigned short* d = dst + (size_t)blockIdx.z * K * N;
    #pragma unroll
    for (int q = 0; q < 4; ++q) {
        int f4 = tid + q * 256;
        int kk = f4 >> 4, nn = (f4 & 15) * 4;
        float4 v = *(const float4*)(s + (size_t)(k0 + kk) * N + n0 + nn);
        int swz = ((nn >> 2) & 7) << 3;
        T[nn + 0][kk ^ swz] = f2bf(v.x);
        T[nn + 1][kk ^ swz] = f2bf(v.y);
        T[nn + 2][kk ^ swz] = f2bf(v.z);
        T[nn + 3][kk ^ swz] = f2bf(v.w);
    }
    __syncthreads();
    #pragma unroll
    for (int q = 0; q < 2; ++q) {
        int s8 = tid + q * 256;
        int nn = s8 >> 3, kc = (s8 & 7) * 8;
        int swz = ((nn >> 2) & 7) << 3;
        *(short8*)(d + (size_t)(n0 + nn) * K + k0 + kc) =
            *(const short8*)&T[nn][kc ^ swz];
    }
}

// ======== shared GEMM body (ring-3, counted vmcnt, XOR swizzle) ========
#define GEMM_BODY(BM, BN)                                                        \
    constexpr int FRM = (BM) / 32;                                               \
    constexpr int FRN = (BN) / 32;                                               \
    constexpr int NIA = (BM) / 64;                                               \
    constexpr int NIB = (BN) / 64;                                               \
    constexpr int NLD = NIA + NIB;                                               \
    __shared__ __align__(16) unsigned short As[3][BM][32];                       \
    __shared__ __align__(16) unsigned short Bs[3][BN][32];                       \
    const int tid = threadIdx.x;                                                 \
    const int lane = tid & 63;                                                   \
    const int w = tid >> 6;                                                      \
    const int wr = w >> 1, wc = w & 1;                                           \
    const int l16 = lane & 15, g = lane >> 4;                                    \
    const int nby = M / (BM);                                                    \
    const int nwg = (N / (BN)) * nby;                                            \
    const int cpx = nwg >> 3;                                                    \
    const int bid = blockIdx.x;                                                  \
    const int sbid = (bid & 7) * cpx + (bid >> 3);                               \
    const int row0 = (sbid % nby) * (BM);                                        \
    const int col0 = (sbid / nby) * (BN);                                        \
    const int srowA = w * ((BM) / 4) + (lane >> 2);                              \
    const int srowB = w * ((BN) / 4) + (lane >> 2);                              \
    const int scol = (((lane & 3) ^ ((lane >> 3) & 3)) << 3);                    \
    const int rslot = ((g ^ ((l16 >> 1) & 3)) << 3);                             \
    const int ldst = (lane & 3) << 3;                                            \
    const unsigned short* ga = A  + (size_t)(row0 + srowA) * KS + (size_t)blockIdx.y * K + scol; \
    const unsigned short* gb = BT + (size_t)(col0 + srowB) * KS + (size_t)blockIdx.y * K + scol; \
    f32x4 acc[FRM][FRN] = {};                                                    \
    const int NT = K >> 5;                                                       \
    _Pragma("unroll")                                                            \
    for (int i = 0; i < NIA; ++i)                                                \
        gload_lds16(ga + (size_t)(i * 16) * KS, &As[0][srowA + i * 16][ldst]);   \
    _Pragma("unroll")                                                            \
    for (int i = 0; i < NIB; ++i)                                                \
        gload_lds16(gb + (size_t)(i * 16) * KS, &Bs[0][srowB + i * 16][ldst]);   \
    for (int t = 0; t < NT; ++t) {                                               \
        const int rb = t % 3;                                                    \
        if (t + 1 < NT) {                                                        \
            const int wb = (t + 1) % 3;                                          \
            const int ko = (t + 1) * 32;                                         \
            _Pragma("unroll")                                                    \
            for (int i = 0; i < NIA; ++i)                                        \
                gload_lds16(ga + ko + (size_t)(i * 16) * KS, &As[wb][srowA + i * 16][ldst]); \
            _Pragma("unroll")                                                    \
            for (int i = 0; i < NIB; ++i)                                        \
                gload_lds16(gb + ko + (size_t)(i * 16) * KS, &Bs[wb][srowB + i * 16][ldst]); \
            asm volatile("s_waitcnt vmcnt(%0)" :: "i"(NLD) : "memory");          \
        } else {                                                                 \
            asm volatile("s_waitcnt vmcnt(0)" ::: "memory");                     \
        }                                                                        \
        __builtin_amdgcn_s_barrier();                                            \
        short8 af[FRM], bf[FRN];                                                 \
        _Pragma("unroll")                                                        \
        for (int i = 0; i < FRM; ++i)                                            \
            af[i] = *(const short8*)&As[rb][wr * ((BM) / 2) + i * 16 + l16][rslot]; \
        _Pragma("unroll")                                                        \
        for (int j = 0; j < FRN; ++j)                                            \
            bf[j] = *(const short8*)&Bs[rb][wc * ((BN) / 2) + j * 16 + l16][rslot]; \
        __builtin_amdgcn_s_setprio(1);                                           \
        _Pragma("unroll")                                                        \
        for (int i = 0; i < FRM; ++i)                                            \
            _Pragma("unroll")                                                    \
            for (int j = 0; j < FRN; ++j)                                        \
                acc[i][j] = __builtin_amdgcn_mfma_f32_16x16x32_bf16(af[i], bf[j], acc[i][j], 0, 0, 0); \
        __builtin_amdgcn_s_setprio(0);                                           \
    }                                                                            \
    float* Cf = (float*)Cout + (size_t)blockIdx.y * M * N;                       \
    _Pragma("unroll")                                                            \
    for (int i = 0; i < FRM; ++i) {                                              \
        _Pragma("unroll")                                                        \
        for (int j = 0; j < FRN; ++j) {                                          \
            _Pragma("unroll")                                                    \
            for (int r = 0; r < 4; ++r) {                                        \
                int row = row0 + wr * ((BM) / 2) + i * 16 + g * 4 + r;           \
                int col = col0 + wc * ((BN) / 2) + j * 16 + l16;                 \
                float v = acc[i][j][r];                                          \
                if (bias)     v += bias[col];                                    \
                if (residual) v += residual[(size_t)row * N + col];              \
                if (relu)     v = fmaxf(v, 0.f);                                 \
                if (OUT_BF16) ((unsigned short*)Cout)[(size_t)row * N + col] = f2bf(v); \
                else          Cf[(size_t)row * N + col] = v;                     \
            }                                                                    \
        }                                                                        \
    }

// head GEMM: 128x128 tile (R12-proven)
template<bool OUT_BF16>
__global__ __launch_bounds__(256)
void gemm_big(const unsigned short* __restrict__ A, const unsigned short* __restrict__ BT,
              const float* __restrict__ bias, const float* __restrict__ residual,
              void* __restrict__ Cout, int M, int N, int K, int KS, int relu)
{
    GEMM_BODY(128, 128)
}

// layer GEMM: 128x64 tile (R13-proven, high occupancy)
template<bool OUT_BF16>
__global__ __launch_bounds__(256, 4)
void gemm_sm(const unsigned short* __restrict__ A, const unsigned short* __restrict__ BT,
             const float* __restrict__ bias, const float* __restrict__ residual,
             void* __restrict__ Cout, int M, int N, int K, int KS, int relu)
{
    GEMM_BODY(128, 64)
}

// ---------------- MFMA flash attention: KVBLK=128, 512 blocks, row-major V ----------------
// V stored ROW-major with per-row XOR chunk swizzle (writes: 4x ds_write_b128
// per thread vs 32x u16 transpose); PV B-frags gathered at use (8x u16/frag).
// Defer-max (T13); setprio around MFMA clusters (T5).
__global__ __launch_bounds__(256)
void attn_flash_k(const unsigned short* __restrict__ qkv, unsigned short* __restrict__ out)
{
    __shared__ unsigned short Ks[128][72];     // [kv][d]
    __shared__ unsigned short Vrm[128][64];    // [kv][d], chunk-swizzled
    __shared__ unsigned short Ps[4][16][136];  // per-wave P [q][kv]

    const int tid = threadIdx.x;
    const int lane = tid & 63;
    const int w = tid >> 6;
    const int l16 = lane & 15, g = lane >> 4;

    const int id = blockIdx.x;
    const int qlow = id & 15;
    const int qb = (id < 256) ? (15 - qlow) : qlow;   // pair (i,i+256) sums to 15
    const int b = (id >> 4) & 1;
    const int h = id >> 5;

    const size_t rstr = 3 * DM;
    const unsigned short* base = qkv + (size_t)b * TSEQ * rstr + h * HDIM;

    const int krow = tid >> 1, kcol = (tid & 1) * 32;
    const int vkv = tid & 127, vdh = (tid >> 7) * 32;
    const int vkey = (vkv + (vkv >> 3)) & 7;

    const int q0 = qb * 64;
    const int nt = (qb >> 1) + 1;

    const int qrow_w = q0 + w * 16 + l16;
    short8 aq0 = *(const short8*)(base + (size_t)qrow_w * rstr + g * 8);
    short8 aq1 = *(const short8*)(base + (size_t)qrow_w * rstr + 32 + g * 8);

    f32x4 acc_o[4] = {};
    float m_r[4] = {-INFINITY, -INFINITY, -INFINITY, -INFINITY};
    float l_r[4] = {};

    short8 kreg[4], vreg[4];
    {   // prologue: tile 0 -> regs
        const unsigned short* kb = base + (size_t)krow * rstr + DM + kcol;
        #pragma unroll
        for (int i = 0; i < 4; ++i) kreg[i] = *(const short8*)(kb + i * 8);
        const unsigned short* vb = base + (size_t)vkv * rstr + 2 * DM + vdh;
        #pragma unroll
        for (int i = 0; i < 4; ++i) vreg[i] = *(const short8*)(vb + i * 8);
    }

    for (int t = 0; t < nt; ++t) {
        #pragma unroll
        for (int i = 0; i < 4; ++i) *(short8*)&Ks[krow][kcol + i * 8] = kreg[i];
        #pragma unroll
        for (int c = 0; c < 4; ++c) {
            int chunk = (vdh >> 3) + c;          // vdh/8 = 0 or 4
            *(short8*)&Vrm[vkv][((chunk ^ vkey) << 3)] = vreg[c];
        }
        __syncthreads();

        if (t + 1 < nt) {   // next tile's loads in flight across compute
            const int kv0n = (t + 1) * 128;
            const unsigned short* kb = base + (size_t)(kv0n + krow) * rstr + DM + kcol;
            #pragma unroll
            for (int i = 0; i < 4; ++i) kreg[i] = *(const short8*)(kb + i * 8);
            const unsigned short* vb = base + (size_t)(kv0n + vkv) * rstr + 2 * DM + vdh;
            #pragma unroll
            for (int i = 0; i < 4; ++i) vreg[i] = *(const short8*)(vb + i * 8);
        }

        const int kv0 = t * 128;
        f32x4 acc_s[8] = {};
        __builtin_amdgcn_s_setprio(1);
        #pragma unroll
        for (int ks = 0; ks < 8; ++ks) {
            short8 bk0 = *(const short8*)&Ks[ks * 16 + l16][g * 8];
            short8 bk1 = *(const short8*)&Ks[ks * 16 + l16][32 + g * 8];
            acc_s[ks] = __builtin_amdgcn_mfma_f32_16x16x32_bf16(aq0, bk0, acc_s[ks], 0, 0, 0);
            acc_s[ks] = __builtin_amdgcn_mfma_f32_16x16x32_bf16(aq1, bk1, acc_s[ks], 0, 0, 0);
        }
        __builtin_amdgcn_s_setprio(0);
        const bool need_mask = (kv0 + 127 > q0 + w * 16);
        float alpha[4];
        #pragma unroll
        for (int r = 0; r < 4; ++r) {
            const int q_abs = q0 + w * 16 + g * 4 + r;
            float s[8];
            #pragma unroll
            for (int ks = 0; ks < 8; ++ks) {
                s[ks] = acc_s[ks][r] * 0.125f;
                if (need_mask && (kv0 + ks * 16 + l16 > q_abs)) s[ks] = -INFINITY;
            }
            float pm = fmaxf(fmaxf(fmaxf(s[0], s[1]), fmaxf(s[2], s[3])),
                             fmaxf(fmaxf(s[4], s[5]), fmaxf(s[6], s[7])));
            #pragma unroll
            for (int msk = 1; msk <= 8; msk <<= 1)
                pm = fmaxf(pm, __shfl_xor(pm, msk));
            if (pm > m_r[r] + 8.f) { alpha[r] = __expf(m_r[r] - pm); m_r[r] = pm; }
            else                   { alpha[r] = 1.f; }
            float p[8], psum = 0.f;
            #pragma unroll
            for (int ks = 0; ks < 8; ++ks) {
                p[ks] = __expf(s[ks] - m_r[r]);
                psum += p[ks];
            }
            #pragma unroll
            for (int msk = 1; msk <= 8; msk <<= 1)
                psum += __shfl_xor(psum, msk);
            l_r[r] = l_r[r] * alpha[r] + psum;
            #pragma unroll
            for (int ks = 0; ks < 8; ++ks)
                Ps[w][g * 4 + r][ks * 16 + l16] = f2bf(p[ks]);
        }
        #pragma unroll
        for (int ds = 0; ds < 4; ++ds)
            #pragma unroll
            for (int r = 0; r < 4; ++r)
                acc_o[ds][r] *= alpha[r];
        short8 ap[4];
        #pragma unroll
        for (int kk = 0; kk < 4; ++kk)
            ap[kk] = *(const short8*)&Ps[w][l16][kk * 32 + g * 8];
        // PV: B-frag gathered from row-major swizzled V
        #pragma unroll
        for (int ds = 0; ds < 4; ++ds) {
            const int dhi = ds * 2 + (l16 >> 3);   // d>>3
            const int dlo = l16 & 7;               // d&7
            #pragma unroll
            for (int kk = 0; kk < 4; ++kk) {
                short8 bv;
                #pragma unroll
                for (int j = 0; j < 8; ++j) {
                    const int kv = kk * 32 + g * 8 + j;
                    const int key = (4 * kk + g + j) & 7;
                    bv[j] = (short)Vrm[kv][(((dhi ^ key) << 3) | dlo)];
                }
                __builtin_amdgcn_s_setprio(1);
                acc_o[ds] = __builtin_amdgcn_mfma_f32_16x16x32_bf16(ap[kk], bv, acc_o[ds], 0, 0, 0);
                __builtin_amdgcn_s_setprio(0);
            }
        }
        __syncthreads();
    }

    #pragma unroll
    for (int ds = 0; ds < 4; ++ds)
        #pragma unroll
        for (int r = 0; r < 4; ++r) {
            int row = q0 + w * 16 + g * 4 + r;
            out[((size_t)b * TSEQ + row) * DM + h * HDIM + ds * 16 + l16] =
                f2bf(acc_o[ds][r] * (1.f / l_r[r]));
        }
}

// ---------------- orchestration ----------------
extern "C" void kernel_launch(void* const* d_in, const int* in_sizes, int n_in,
                              void* d_out, int out_size, void* d_ws, size_t ws_size,
                              hipStream_t stream)
{
    const int*   idx    = (const int*)  d_in[0];
    const float* embed  = (const float*)d_in[1];
    const float* Wqkv   = (const float*)d_in[2];
    const float* Wproj  = (const float*)d_in[3];
    const float* bproj  = (const float*)d_in[4];
    const float* ln1_g  = (const float*)d_in[5];
    const float* ln1_b  = (const float*)d_in[6];
    const float* ln2_g  = (const float*)d_in[7];
    const float* ln2_b  = (const float*)d_in[8];
    const float* W1     = (const float*)d_in[9];
    const float* b1     = (const float*)d_in[10];
    const float* W2     = (const float*)d_in[11];
    const float* b2     = (const float*)d_in[12];
    const float* lnf_g  = (const float*)d_in[13];
    const float* lnf_b  = (const float*)d_in[14];
    const float* Whead  = (const float*)d_in[15];
    float* out = (float*)d_out;

    float* X = (float*)d_ws;
    float* PK = X + (size_t)NROWS * DM;
    unsigned short* u = (unsigned short*)(PK + (size_t)4 * NROWS * DM);
    unsigned short* XN     = u;  u += (size_t)NROWS * DM;
    unsigned short* QKVb   = u;  u += (size_t)NROWS * 3 * DM;
    unsigned short* ATT    = u;  u += (size_t)NROWS * DM;
    unsigned short* FFH    = u;  u += (size_t)NROWS * DFFN;
    unsigned short* WqkvT  = u;  u += (size_t)NLAYER * 3 * DM * DM;
    unsigned short* WprojT = u;  u += (size_t)NLAYER * DM * DM;
    unsigned short* W1T    = u;  u += (size_t)NLAYER * DFFN * DM;
    unsigned short* W2T    = u;  u += (size_t)NLAYER * DM * DFFN;
    unsigned short* WheadT = u;  u += (size_t)NVOC * DM;

    convt_k<<<dim3(3 * DM / 64, DM / 64, NLAYER), 256, 0, stream>>>(Wqkv,  WqkvT,  DM,   3 * DM);
    convt_k<<<dim3(DM / 64,     DM / 64, NLAYER), 256, 0, stream>>>(Wproj, WprojT, DM,   DM);
    convt_k<<<dim3(DFFN / 64,   DM / 64, NLAYER), 256, 0, stream>>>(W1,    W1T,    DM,   DFFN);
    convt_k<<<dim3(DM / 64,   DFFN / 64, NLAYER), 256, 0, stream>>>(W2,    W2T,    DFFN, DM);
    convt_k<<<dim3(NVOC / 64,   DM / 64, 1),      256, 0, stream>>>(Whead, WheadT, DM,   NVOC);

    embed_pos_k<<<NROWS, 256, 0, stream>>>(idx, embed, X);
    layernorm_k<<<NROWS, 256, 0, stream>>>(X, ln1_g, ln1_b, XN);   // layer-0 ln1

    for (int l = 0; l < NLAYER; ++l) {
        const unsigned short* wqkvT_l  = WqkvT  + (size_t)l * 3 * DM * DM;
        const unsigned short* wprojT_l = WprojT + (size_t)l * DM * DM;
        const unsigned short* w1T_l    = W1T    + (size_t)l * DFFN * DM;
        const unsigned short* w2T_l    = W2T    + (size_t)l * DM * DFFN;
        const float* bproj_l = bproj + (size_t)l * DM;
        const float* b1_l = b1 + (size_t)l * DFFN;
        const float* b2_l = b2 + (size_t)l * DM;

        {   // qkv = ln1(x) @ Wqkv  (bf16 out): 768 blocks
            int nwg = (NROWS / 128) * (3 * DM / 64);
            gemm_sm<true><<<nwg, 256, 0, stream>>>(XN, wqkvT_l, nullptr, nullptr,
                                                   QKVb, NROWS, 3 * DM, DM, DM, 0);
        }
        {   // flash attention: 512 blocks, 2+/CU, balanced qb pairs
            attn_flash_k<<<512, 256, 0, stream>>>(QKVb, ATT);
        }
        {   // proj: split-K=2 -> partials (512 blocks); fused reduce + ln2
            dim3 grid((NROWS / 128) * (DM / 64), 2);
            gemm_sm<false><<<grid, 256, 0, stream>>>(ATT, wprojT_l, nullptr, nullptr,
                                                     PK, NROWS, DM, 512, DM, 0);
            reduce_ln_k<<<NROWS, 256, 0, stream>>>(PK, 2, bproj_l, X,
                                                   ln2_g + (size_t)l * DM,
                                                   ln2_b + (size_t)l * DM, XN);
        }
        {   // ffh = relu(ln2 @ W1 + b1): 1024 blocks
            int nwg = (NROWS / 128) * (DFFN / 64);
            gemm_sm<true><<<nwg, 256, 0, stream>>>(XN, w1T_l, b1_l, nullptr,
                                                   FFH, NROWS, DFFN, DM, DM, 1);
        }
        {   // ffn2: split-K=2 (K=2048 each) -> partials (512 blocks); reduce + ln1[l+1]/lnf
            dim3 grid((NROWS / 128) * (DM / 64), 2);
            gemm_sm<false><<<grid, 256, 0, stream>>>(FFH, w2T_l, nullptr, nullptr,
                                                     PK, NROWS, DM, 2048, DFFN, 0);
            const float* ng = (l + 1 < NLAYER) ? ln1_g + (size_t)(l + 1) * DM : lnf_g;
            const float* nb = (l + 1 < NLAYER) ? ln1_b + (size_t)(l + 1) * DM : lnf_b;
            reduce_ln_k<<<NROWS, 256, 0, stream>>>(PK, 2, b2_l, X, ng, nb, XN);
        }
    }

    {   // logits = lnf(x) @ Whead: 128^2 tile (R12-proven for HBM-streaming B)
        int nwg = (NROWS / 128) * (NVOC / 128);
        gemm_big<false><<<nwg, 256, 0, stream>>>(XN, WheadT, nullptr, nullptr,
                                                 out, NROWS, NVOC, DM, DM, 0);
    }
}

// Round 16
// 1653.284 us; speedup vs baseline: 1.0311x; 1.0311x over previous
//
#include <hip/hip_runtime.h>
#include <cstddef>

#define DM    1024
#define TSEQ  1024
#define NB    2
#define NHEAD 16
#define HDIM  64
#define NLAYER 8
#define DFFN  4096
#define NVOC  32000
#define NROWS (NB*TSEQ)

typedef __attribute__((ext_vector_type(8))) short short8;
typedef __attribute__((ext_vector_type(4))) float f32x4;

static __device__ __forceinline__ unsigned short f2bf(float f) {
    union { float f; unsigned int u; } v; v.f = f;
    unsigned int r = v.u + 0x7FFF + ((v.u >> 16) & 1);   // RNE
    return (unsigned short)(r >> 16);
}

static __device__ __forceinline__ void gload_lds16(const void* g, void* l) {
    __builtin_amdgcn_global_load_lds(
        (const __attribute__((address_space(1))) unsigned int*)g,
        (__attribute__((address_space(3))) unsigned int*)l, 16, 0, 0);
}

// ---------------- embedding + positional encoding (f32 out) ----------------
__global__ __launch_bounds__(256)
void embed_pos_k(const int* __restrict__ idx, const float* __restrict__ embed,
                 float* __restrict__ x)
{
    int row = blockIdx.x;
    int t   = row & (TSEQ - 1);
    int tid = threadIdx.x;
    int token = idx[row];
    const float* er = embed + (size_t)token * DM;
    float* xr = x + (size_t)row * DM;
    const float neg_ln1e4_over_d = -9.210340371976184f / (float)DM;
    for (int i = tid; i < DM; i += 256) {
        int half = i >> 1;
        float div = expf((float)(2 * half) * neg_ln1e4_over_d);
        float ang = (float)t * div;
        float pe = (i & 1) ? cosf(ang) : sinf(ang);
        xr[i] = er[i] + pe;
    }
}

// ---------------- layernorm (f32 in, bf16 out) ----------------
__global__ __launch_bounds__(256)
void layernorm_k(const float* __restrict__ x, const float* __restrict__ g,
                 const float* __restrict__ b, unsigned short* __restrict__ y)
{
    int row = blockIdx.x;
    int tid = threadIdx.x;
    const float* xr = x + (size_t)row * DM;
    unsigned short* yr = y + (size_t)row * DM;
    float vals[4];
    float s = 0.f;
    #pragma unroll
    for (int i = 0; i < 4; ++i) { vals[i] = xr[tid + 256 * i]; s += vals[i]; }
    __shared__ float red[256];
    red[tid] = s; __syncthreads();
    for (int st = 128; st > 0; st >>= 1) {
        if (tid < st) red[tid] += red[tid + st];
        __syncthreads();
    }
    float mu = red[0] * (1.f / DM);
    __syncthreads();
    float v = 0.f;
    #pragma unroll
    for (int i = 0; i < 4; ++i) { float d = vals[i] - mu; v += d * d; }
    red[tid] = v; __syncthreads();
    for (int st = 128; st > 0; st >>= 1) {
        if (tid < st) red[tid] += red[tid + st];
        __syncthreads();
    }
    float rstd = rsqrtf(red[0] * (1.f / DM) + 1e-5f);
    #pragma unroll
    for (int i = 0; i < 4; ++i) {
        int c = tid + 256 * i;
        yr[c] = f2bf((vals[i] - mu) * rstd * g[c] + b[c]);
    }
}

// ---------------- fused split-K reduce + residual + bias + layernorm ----------------
__global__ __launch_bounds__(256)
void reduce_ln_k(const float* __restrict__ P, int nsplit, const float* __restrict__ bias,
                 float* __restrict__ X, const float* __restrict__ g,
                 const float* __restrict__ b, unsigned short* __restrict__ XN)
{
    const int row = blockIdx.x;
    const int tid = threadIdx.x;
    const size_t off4 = (size_t)row * 256 + tid;
    const size_t tot4 = (size_t)NROWS * 256;

    float4 v = *((const float4*)X + off4);
    float4 bb = *((const float4*)bias + tid);
    v.x += bb.x; v.y += bb.y; v.z += bb.z; v.w += bb.w;
    for (int s = 0; s < nsplit; ++s) {
        float4 p = *((const float4*)P + s * tot4 + off4);
        v.x += p.x; v.y += p.y; v.z += p.z; v.w += p.w;
    }
    *((float4*)X + off4) = v;

    __shared__ float red[256];
    red[tid] = v.x + v.y + v.z + v.w;
    __syncthreads();
    for (int st = 128; st > 0; st >>= 1) {
        if (tid < st) red[tid] += red[tid + st];
        __syncthreads();
    }
    float mu = red[0] * (1.f / DM);
    __syncthreads();
    float4 d = make_float4(v.x - mu, v.y - mu, v.z - mu, v.w - mu);
    red[tid] = d.x * d.x + d.y * d.y + d.z * d.z + d.w * d.w;
    __syncthreads();
    for (int st = 128; st > 0; st >>= 1) {
        if (tid < st) red[tid] += red[tid + st];
        __syncthreads();
    }
    float rstd = rsqrtf(red[0] * (1.f / DM) + 1e-5f);
    float4 gg = *((const float4*)g + tid);
    float4 bbn = *((const float4*)b + tid);
    unsigned short o[4];
    o[0] = f2bf(d.x * rstd * gg.x + bbn.x);
    o[1] = f2bf(d.y * rstd * gg.y + bbn.y);
    o[2] = f2bf(d.z * rstd * gg.z + bbn.z);
    o[3] = f2bf(d.w * rstd * gg.w + bbn.w);
    *(ushort4*)(XN + (size_t)row * DM + tid * 4) = *(ushort4*)o;
}

// ---------------- weight convert+transpose: f32 [K][N] -> bf16 [N][K] ----------------
__global__ __launch_bounds__(256)
void convt_k(const float* __restrict__ src, unsigned short* __restrict__ dst,
             int K, int N)
{
    __shared__ __align__(16) unsigned short T[64][72];
    const int tid = threadIdx.x;
    const int n0 = blockIdx.x * 64, k0 = blockIdx.y * 64;
    const float* s = src + (size_t)blockIdx.z * K * N;
    unsigned short* d = dst + (size_t)blockIdx.z * K * N;
    #pragma unroll
    for (int q = 0; q < 4; ++q) {
        int f4 = tid + q * 256;
        int kk = f4 >> 4, nn = (f4 & 15) * 4;
        float4 v = *(const float4*)(s + (size_t)(k0 + kk) * N + n0 + nn);
        int swz = ((nn >> 2) & 7) << 3;
        T[nn + 0][kk ^ swz] = f2bf(v.x);
        T[nn + 1][kk ^ swz] = f2bf(v.y);
        T[nn + 2][kk ^ swz] = f2bf(v.z);
        T[nn + 3][kk ^ swz] = f2bf(v.w);
    }
    __syncthreads();
    #pragma unroll
    for (int q = 0; q < 2; ++q) {
        int s8 = tid + q * 256;
        int nn = s8 >> 3, kc = (s8 & 7) * 8;
        int swz = ((nn >> 2) & 7) << 3;
        *(short8*)(d + (size_t)(n0 + nn) * K + k0 + kc) =
            *(const short8*)&T[nn][kc ^ swz];
    }
}

// ======== shared GEMM body (ring-3, counted vmcnt, XOR swizzle) ========
#define GEMM_BODY(BM, BN)                                                        \
    constexpr int FRM = (BM) / 32;                                               \
    constexpr int FRN = (BN) / 32;                                               \
    constexpr int NIA = (BM) / 64;                                               \
    constexpr int NIB = (BN) / 64;                                               \
    constexpr int NLD = NIA + NIB;                                               \
    __shared__ __align__(16) unsigned short As[3][BM][32];                       \
    __shared__ __align__(16) unsigned short Bs[3][BN][32];                       \
    const int tid = threadIdx.x;                                                 \
    const int lane = tid & 63;                                                   \
    const int w = tid >> 6;                                                      \
    const int wr = w >> 1, wc = w & 1;                                           \
    const int l16 = lane & 15, g = lane >> 4;                                    \
    const int nby = M / (BM);                                                    \
    const int nwg = (N / (BN)) * nby;                                            \
    const int cpx = nwg >> 3;                                                    \
    const int bid = blockIdx.x;                                                  \
    const int sbid = (bid & 7) * cpx + (bid >> 3);                               \
    const int row0 = (sbid % nby) * (BM);                                        \
    const int col0 = (sbid / nby) * (BN);                                        \
    const int srowA = w * ((BM) / 4) + (lane >> 2);                              \
    const int srowB = w * ((BN) / 4) + (lane >> 2);                              \
    const int scol = (((lane & 3) ^ ((lane >> 3) & 3)) << 3);                    \
    const int rslot = ((g ^ ((l16 >> 1) & 3)) << 3);                             \
    const int ldst = (lane & 3) << 3;                                            \
    const unsigned short* ga = A  + (size_t)(row0 + srowA) * KS + (size_t)blockIdx.y * K + scol; \
    const unsigned short* gb = BT + (size_t)(col0 + srowB) * KS + (size_t)blockIdx.y * K + scol; \
    f32x4 acc[FRM][FRN] = {};                                                    \
    const int NT = K >> 5;                                                       \
    _Pragma("unroll")                                                            \
    for (int i = 0; i < NIA; ++i)                                                \
        gload_lds16(ga + (size_t)(i * 16) * KS, &As[0][srowA + i * 16][ldst]);   \
    _Pragma("unroll")                                                            \
    for (int i = 0; i < NIB; ++i)                                                \
        gload_lds16(gb + (size_t)(i * 16) * KS, &Bs[0][srowB + i * 16][ldst]);   \
    for (int t = 0; t < NT; ++t) {                                               \
        const int rb = t % 3;                                                    \
        if (t + 1 < NT) {                                                        \
            const int wb = (t + 1) % 3;                                          \
            const int ko = (t + 1) * 32;                                         \
            _Pragma("unroll")                                                    \
            for (int i = 0; i < NIA; ++i)                                        \
                gload_lds16(ga + ko + (size_t)(i * 16) * KS, &As[wb][srowA + i * 16][ldst]); \
            _Pragma("unroll")                                                    \
            for (int i = 0; i < NIB; ++i)                                        \
                gload_lds16(gb + ko + (size_t)(i * 16) * KS, &Bs[wb][srowB + i * 16][ldst]); \
            asm volatile("s_waitcnt vmcnt(%0)" :: "i"(NLD) : "memory");          \
        } else {                                                                 \
            asm volatile("s_waitcnt vmcnt(0)" ::: "memory");                     \
        }                                                                        \
        __builtin_amdgcn_s_barrier();                                            \
        short8 af[FRM], bf[FRN];                                                 \
        _Pragma("unroll")                                                        \
        for (int i = 0; i < FRM; ++i)                                            \
            af[i] = *(const short8*)&As[rb][wr * ((BM) / 2) + i * 16 + l16][rslot]; \
        _Pragma("unroll")                                                        \
        for (int j = 0; j < FRN; ++j)                                            \
            bf[j] = *(const short8*)&Bs[rb][wc * ((BN) / 2) + j * 16 + l16][rslot]; \
        __builtin_amdgcn_s_setprio(1);                                           \
        _Pragma("unroll")                                                        \
        for (int i = 0; i < FRM; ++i)                                            \
            _Pragma("unroll")                                                    \
            for (int j = 0; j < FRN; ++j)                                        \
                acc[i][j] = __builtin_amdgcn_mfma_f32_16x16x32_bf16(af[i], bf[j], acc[i][j], 0, 0, 0); \
        __builtin_amdgcn_s_setprio(0);                                           \
    }                                                                            \
    float* Cf = (float*)Cout + (size_t)blockIdx.y * M * N;                       \
    _Pragma("unroll")                                                            \
    for (int i = 0; i < FRM; ++i) {                                              \
        _Pragma("unroll")                                                        \
        for (int j = 0; j < FRN; ++j) {                                          \
            _Pragma("unroll")                                                    \
            for (int r = 0; r < 4; ++r) {                                        \
                int row = row0 + wr * ((BM) / 2) + i * 16 + g * 4 + r;           \
                int col = col0 + wc * ((BN) / 2) + j * 16 + l16;                 \
                float v = acc[i][j][r];                                          \
                if (bias)     v += bias[col];                                    \
                if (residual) v += residual[(size_t)row * N + col];              \
                if (relu)     v = fmaxf(v, 0.f);                                 \
                if (OUT_BF16) ((unsigned short*)Cout)[(size_t)row * N + col] = f2bf(v); \
                else          Cf[(size_t)row * N + col] = v;                     \
            }                                                                    \
        }                                                                        \
    }

// head GEMM: 128x128 tile (R12-proven)
template<bool OUT_BF16>
__global__ __launch_bounds__(256)
void gemm_big(const unsigned short* __restrict__ A, const unsigned short* __restrict__ BT,
              const float* __restrict__ bias, const float* __restrict__ residual,
              void* __restrict__ Cout, int M, int N, int K, int KS, int relu)
{
    GEMM_BODY(128, 128)
}

// layer GEMM: 128x64 tile (R13-proven, high occupancy)
template<bool OUT_BF16>
__global__ __launch_bounds__(256, 4)
void gemm_sm(const unsigned short* __restrict__ A, const unsigned short* __restrict__ BT,
             const float* __restrict__ bias, const float* __restrict__ residual,
             void* __restrict__ Cout, int M, int N, int K, int KS, int relu)
{
    GEMM_BODY(128, 64)
}

// ---------------- MFMA flash attention: KVBLK=128, 512 blocks (R14) + QK setprio ----------------
__global__ __launch_bounds__(256)
void attn_flash_k(const unsigned short* __restrict__ qkv, unsigned short* __restrict__ out)
{
    __shared__ unsigned short Ks[128][72];     // [kv][d]
    __shared__ unsigned short Vt[64][136];     // [d][kv]
    __shared__ unsigned short Ps[4][16][136];  // per-wave P [q][kv]

    const int tid = threadIdx.x;
    const int lane = tid & 63;
    const int w = tid >> 6;
    const int l16 = lane & 15, g = lane >> 4;

    const int id = blockIdx.x;
    const int qlow = id & 15;
    const int qb = (id < 256) ? (15 - qlow) : qlow;   // pair (i,i+256) sums to 15
    const int b = (id >> 4) & 1;
    const int h = id >> 5;

    const size_t rstr = 3 * DM;
    const unsigned short* base = qkv + (size_t)b * TSEQ * rstr + h * HDIM;

    const int krow = tid >> 1, kcol = (tid & 1) * 32;
    const int vkv = tid & 127, vdh = (tid >> 7) * 32;

    const int q0 = qb * 64;
    const int nt = (qb >> 1) + 1;

    const int qrow_w = q0 + w * 16 + l16;
    short8 aq0 = *(const short8*)(base + (size_t)qrow_w * rstr + g * 8);
    short8 aq1 = *(const short8*)(base + (size_t)qrow_w * rstr + 32 + g * 8);

    f32x4 acc_o[4] = {};
    float m_r[4] = {-INFINITY, -INFINITY, -INFINITY, -INFINITY};
    float l_r[4] = {};

    short8 kreg[4], vreg[4];
    {   // prologue: tile 0 -> regs
        const unsigned short* kb = base + (size_t)krow * rstr + DM + kcol;
        #pragma unroll
        for (int i = 0; i < 4; ++i) kreg[i] = *(const short8*)(kb + i * 8);
        const unsigned short* vb = base + (size_t)vkv * rstr + 2 * DM + vdh;
        #pragma unroll
        for (int i = 0; i < 4; ++i) vreg[i] = *(const short8*)(vb + i * 8);
    }

    for (int t = 0; t < nt; ++t) {
        #pragma unroll
        for (int i = 0; i < 4; ++i) *(short8*)&Ks[krow][kcol + i * 8] = kreg[i];
        #pragma unroll
        for (int jj = 0; jj < 4; ++jj)
            #pragma unroll
            for (int j = 0; j < 8; ++j)
                Vt[vdh + jj * 8 + j][vkv] = (unsigned short)vreg[jj][j];
        __syncthreads();

        if (t + 1 < nt) {   // next tile's loads in flight across compute
            const int kv0n = (t + 1) * 128;
            const unsigned short* kb = base + (size_t)(kv0n + krow) * rstr + DM + kcol;
            #pragma unroll
            for (int i = 0; i < 4; ++i) kreg[i] = *(const short8*)(kb + i * 8);
            const unsigned short* vb = base + (size_t)(kv0n + vkv) * rstr + 2 * DM + vdh;
            #pragma unroll
            for (int i = 0; i < 4; ++i) vreg[i] = *(const short8*)(vb + i * 8);
        }

        const int kv0 = t * 128;
        f32x4 acc_s[8] = {};
        __builtin_amdgcn_s_setprio(1);   // T5: QK^T MFMA cluster (m191 regime)
        #pragma unroll
        for (int ks = 0; ks < 8; ++ks) {
            short8 bk0 = *(const short8*)&Ks[ks * 16 + l16][g * 8];
            short8 bk1 = *(const short8*)&Ks[ks * 16 + l16][32 + g * 8];
            acc_s[ks] = __builtin_amdgcn_mfma_f32_16x16x32_bf16(aq0, bk0, acc_s[ks], 0, 0, 0);
            acc_s[ks] = __builtin_amdgcn_mfma_f32_16x16x32_bf16(aq1, bk1, acc_s[ks], 0, 0, 0);
        }
        __builtin_amdgcn_s_setprio(0);
        const bool need_mask = (kv0 + 127 > q0 + w * 16);
        float alpha[4];
        #pragma unroll
        for (int r = 0; r < 4; ++r) {
            const int q_abs = q0 + w * 16 + g * 4 + r;
            float s[8];
            #pragma unroll
            for (int ks = 0; ks < 8; ++ks) {
                s[ks] = acc_s[ks][r] * 0.125f;
                if (need_mask && (kv0 + ks * 16 + l16 > q_abs)) s[ks] = -INFINITY;
            }
            float pm = fmaxf(fmaxf(fmaxf(s[0], s[1]), fmaxf(s[2], s[3])),
                             fmaxf(fmaxf(s[4], s[5]), fmaxf(s[6], s[7])));
            #pragma unroll
            for (int msk = 1; msk <= 8; msk <<= 1)
                pm = fmaxf(pm, __shfl_xor(pm, msk));
            // defer-max: only rescale when max grew by > 8 (T13)
            if (pm > m_r[r] + 8.f) { alpha[r] = __expf(m_r[r] - pm); m_r[r] = pm; }
            else                   { alpha[r] = 1.f; }
            float p[8], psum = 0.f;
            #pragma unroll
            for (int ks = 0; ks < 8; ++ks) {
                p[ks] = __expf(s[ks] - m_r[r]);   // masked: exp(-inf)=0
                psum += p[ks];
            }
            #pragma unroll
            for (int msk = 1; msk <= 8; msk <<= 1)
                psum += __shfl_xor(psum, msk);
            l_r[r] = l_r[r] * alpha[r] + psum;
            #pragma unroll
            for (int ks = 0; ks < 8; ++ks)
                Ps[w][g * 4 + r][ks * 16 + l16] = f2bf(p[ks]);
        }
        #pragma unroll
        for (int ds = 0; ds < 4; ++ds)
            #pragma unroll
            for (int r = 0; r < 4; ++r)
                acc_o[ds][r] *= alpha[r];
        short8 ap[4];
        #pragma unroll
        for (int kk = 0; kk < 4; ++kk)
            ap[kk] = *(const short8*)&Ps[w][l16][kk * 32 + g * 8];
        #pragma unroll
        for (int ds = 0; ds < 4; ++ds) {
            #pragma unroll
            for (int kk = 0; kk < 4; ++kk) {
                short8 bv = *(const short8*)&Vt[ds * 16 + l16][kk * 32 + g * 8];
                acc_o[ds] = __builtin_amdgcn_mfma_f32_16x16x32_bf16(ap[kk], bv, acc_o[ds], 0, 0, 0);
            }
        }
        __syncthreads();
    }

    #pragma unroll
    for (int ds = 0; ds < 4; ++ds)
        #pragma unroll
        for (int r = 0; r < 4; ++r) {
            int row = q0 + w * 16 + g * 4 + r;
            out[((size_t)b * TSEQ + row) * DM + h * HDIM + ds * 16 + l16] =
                f2bf(acc_o[ds][r] * (1.f / l_r[r]));
        }
}

// ---------------- orchestration ----------------
extern "C" void kernel_launch(void* const* d_in, const int* in_sizes, int n_in,
                              void* d_out, int out_size, void* d_ws, size_t ws_size,
                              hipStream_t stream)
{
    const int*   idx    = (const int*)  d_in[0];
    const float* embed  = (const float*)d_in[1];
    const float* Wqkv   = (const float*)d_in[2];
    const float* Wproj  = (const float*)d_in[3];
    const float* bproj  = (const float*)d_in[4];
    const float* ln1_g  = (const float*)d_in[5];
    const float* ln1_b  = (const float*)d_in[6];
    const float* ln2_g  = (const float*)d_in[7];
    const float* ln2_b  = (const float*)d_in[8];
    const float* W1     = (const float*)d_in[9];
    const float* b1     = (const float*)d_in[10];
    const float* W2     = (const float*)d_in[11];
    const float* b2     = (const float*)d_in[12];
    const float* lnf_g  = (const float*)d_in[13];
    const float* lnf_b  = (const float*)d_in[14];
    const float* Whead  = (const float*)d_in[15];
    float* out = (float*)d_out;

    float* X = (float*)d_ws;
    float* PK = X + (size_t)NROWS * DM;
    unsigned short* u = (unsigned short*)(PK + (size_t)4 * NROWS * DM);
    unsigned short* XN     = u;  u += (size_t)NROWS * DM;
    unsigned short* QKVb   = u;  u += (size_t)NROWS * 3 * DM;
    unsigned short* ATT    = u;  u += (size_t)NROWS * DM;
    unsigned short* FFH    = u;  u += (size_t)NROWS * DFFN;
    unsigned short* WqkvT  = u;  u += (size_t)NLAYER * 3 * DM * DM;
    unsigned short* WprojT = u;  u += (size_t)NLAYER * DM * DM;
    unsigned short* W1T    = u;  u += (size_t)NLAYER * DFFN * DM;
    unsigned short* W2T    = u;  u += (size_t)NLAYER * DM * DFFN;
    unsigned short* WheadT = u;  u += (size_t)NVOC * DM;

    convt_k<<<dim3(3 * DM / 64, DM / 64, NLAYER), 256, 0, stream>>>(Wqkv,  WqkvT,  DM,   3 * DM);
    convt_k<<<dim3(DM / 64,     DM / 64, NLAYER), 256, 0, stream>>>(Wproj, WprojT, DM,   DM);
    convt_k<<<dim3(DFFN / 64,   DM / 64, NLAYER), 256, 0, stream>>>(W1,    W1T,    DM,   DFFN);
    convt_k<<<dim3(DM / 64,   DFFN / 64, NLAYER), 256, 0, stream>>>(W2,    W2T,    DFFN, DM);
    convt_k<<<dim3(NVOC / 64,   DM / 64, 1),      256, 0, stream>>>(Whead, WheadT, DM,   NVOC);

    embed_pos_k<<<NROWS, 256, 0, stream>>>(idx, embed, X);
    layernorm_k<<<NROWS, 256, 0, stream>>>(X, ln1_g, ln1_b, XN);   // layer-0 ln1

    for (int l = 0; l < NLAYER; ++l) {
        const unsigned short* wqkvT_l  = WqkvT  + (size_t)l * 3 * DM * DM;
        const unsigned short* wprojT_l = WprojT + (size_t)l * DM * DM;
        const unsigned short* w1T_l    = W1T    + (size_t)l * DFFN * DM;
        const unsigned short* w2T_l    = W2T    + (size_t)l * DM * DFFN;
        const float* bproj_l = bproj + (size_t)l * DM;
        const float* b1_l = b1 + (size_t)l * DFFN;
        const float* b2_l = b2 + (size_t)l * DM;

        {   // qkv = ln1(x) @ Wqkv  (bf16 out): 768 blocks
            int nwg = (NROWS / 128) * (3 * DM / 64);
            gemm_sm<true><<<nwg, 256, 0, stream>>>(XN, wqkvT_l, nullptr, nullptr,
                                                   QKVb, NROWS, 3 * DM, DM, DM, 0);
        }
        {   // flash attention: 512 blocks, 2/CU, balanced qb pairs
            attn_flash_k<<<512, 256, 0, stream>>>(QKVb, ATT);
        }
        {   // proj: split-K=2 -> partials (512 blocks); fused reduce + ln2
            dim3 grid((NROWS / 128) * (DM / 64), 2);
            gemm_sm<false><<<grid, 256, 0, stream>>>(ATT, wprojT_l, nullptr, nullptr,
                                                     PK, NROWS, DM, 512, DM, 0);
            reduce_ln_k<<<NROWS, 256, 0, stream>>>(PK, 2, bproj_l, X,
                                                   ln2_g + (size_t)l * DM,
                                                   ln2_b + (size_t)l * DM, XN);
        }
        {   // ffh = relu(ln2 @ W1 + b1): 1024 blocks
            int nwg = (NROWS / 128) * (DFFN / 64);
            gemm_sm<true><<<nwg, 256, 0, stream>>>(XN, w1T_l, b1_l, nullptr,
                                                   FFH, NROWS, DFFN, DM, DM, 1);
        }
        {   // ffn2: split-K=4 -> partials (1024 blocks); reduce + ln1[l+1]/lnf
            dim3 grid((NROWS / 128) * (DM / 64), 4);
            gemm_sm<false><<<grid, 256, 0, stream>>>(FFH, w2T_l, nullptr, nullptr,
                                                     PK, NROWS, DM, 1024, DFFN, 0);
            const float* ng = (l + 1 < NLAYER) ? ln1_g + (size_t)(l + 1) * DM : lnf_g;
            const float* nb = (l + 1 < NLAYER) ? ln1_b + (size_t)(l + 1) * DM : lnf_b;
            reduce_ln_k<<<NROWS, 256, 0, stream>>>(PK, 4, b2_l, X, ng, nb, XN);
        }
    }

    {   // logits = lnf(x) @ Whead: 128^2 tile (R12-proven for HBM-streaming B)
        int nwg = (NROWS / 128) * (NVOC / 128);
        gemm_big<false><<<nwg, 256, 0, stream>>>(XN, WheadT, nullptr, nullptr,
                                                 out, NROWS, NVOC, DM, DM, 0);
    }
}

// Round 17
// 1640.058 us; speedup vs baseline: 1.0394x; 1.0081x over previous
//
#include <hip/hip_runtime.h>
#include <cstddef>

#define DM    1024
#define TSEQ  1024
#define NB    2
#define NHEAD 16
#define HDIM  64
#define NLAYER 8
#define DFFN  4096
#define NVOC  32000
#define NROWS (NB*TSEQ)

typedef __attribute__((ext_vector_type(8))) short short8;
typedef __attribute__((ext_vector_type(4))) float f32x4;

static __device__ __forceinline__ unsigned short f2bf(float f) {
    union { float f; unsigned int u; } v; v.f = f;
    unsigned int r = v.u + 0x7FFF + ((v.u >> 16) & 1);   // RNE
    return (unsigned short)(r >> 16);
}

static __device__ __forceinline__ void gload_lds16(const void* g, void* l) {
    __builtin_amdgcn_global_load_lds(
        (const __attribute__((address_space(1))) unsigned int*)g,
        (__attribute__((address_space(3))) unsigned int*)l, 16, 0, 0);
}

// ---------------- embedding + positional encoding (f32 out) ----------------
__global__ __launch_bounds__(256)
void embed_pos_k(const int* __restrict__ idx, const float* __restrict__ embed,
                 float* __restrict__ x)
{
    int row = blockIdx.x;
    int t   = row & (TSEQ - 1);
    int tid = threadIdx.x;
    int token = idx[row];
    const float* er = embed + (size_t)token * DM;
    float* xr = x + (size_t)row * DM;
    const float neg_ln1e4_over_d = -9.210340371976184f / (float)DM;
    for (int i = tid; i < DM; i += 256) {
        int half = i >> 1;
        float div = expf((float)(2 * half) * neg_ln1e4_over_d);
        float ang = (float)t * div;
        float pe = (i & 1) ? cosf(ang) : sinf(ang);
        xr[i] = er[i] + pe;
    }
}

// ---------------- layernorm (f32 in, bf16 out) ----------------
__global__ __launch_bounds__(256)
void layernorm_k(const float* __restrict__ x, const float* __restrict__ g,
                 const float* __restrict__ b, unsigned short* __restrict__ y)
{
    int row = blockIdx.x;
    int tid = threadIdx.x;
    const float* xr = x + (size_t)row * DM;
    unsigned short* yr = y + (size_t)row * DM;
    float vals[4];
    float s = 0.f;
    #pragma unroll
    for (int i = 0; i < 4; ++i) { vals[i] = xr[tid + 256 * i]; s += vals[i]; }
    __shared__ float red[256];
    red[tid] = s; __syncthreads();
    for (int st = 128; st > 0; st >>= 1) {
        if (tid < st) red[tid] += red[tid + st];
        __syncthreads();
    }
    float mu = red[0] * (1.f / DM);
    __syncthreads();
    float v = 0.f;
    #pragma unroll
    for (int i = 0; i < 4; ++i) { float d = vals[i] - mu; v += d * d; }
    red[tid] = v; __syncthreads();
    for (int st = 128; st > 0; st >>= 1) {
        if (tid < st) red[tid] += red[tid + st];
        __syncthreads();
    }
    float rstd = rsqrtf(red[0] * (1.f / DM) + 1e-5f);
    #pragma unroll
    for (int i = 0; i < 4; ++i) {
        int c = tid + 256 * i;
        yr[c] = f2bf((vals[i] - mu) * rstd * g[c] + b[c]);
    }
}

// ---------------- fused split-K reduce + residual + bias + layernorm ----------------
__global__ __launch_bounds__(256)
void reduce_ln_k(const float* __restrict__ P, int nsplit, const float* __restrict__ bias,
                 float* __restrict__ X, const float* __restrict__ g,
                 const float* __restrict__ b, unsigned short* __restrict__ XN)
{
    const int row = blockIdx.x;
    const int tid = threadIdx.x;
    const size_t off4 = (size_t)row * 256 + tid;
    const size_t tot4 = (size_t)NROWS * 256;

    float4 v = *((const float4*)X + off4);
    float4 bb = *((const float4*)bias + tid);
    v.x += bb.x; v.y += bb.y; v.z += bb.z; v.w += bb.w;
    for (int s = 0; s < nsplit; ++s) {
        float4 p = *((const float4*)P + s * tot4 + off4);
        v.x += p.x; v.y += p.y; v.z += p.z; v.w += p.w;
    }
    *((float4*)X + off4) = v;

    __shared__ float red[256];
    red[tid] = v.x + v.y + v.z + v.w;
    __syncthreads();
    for (int st = 128; st > 0; st >>= 1) {
        if (tid < st) red[tid] += red[tid + st];
        __syncthreads();
    }
    float mu = red[0] * (1.f / DM);
    __syncthreads();
    float4 d = make_float4(v.x - mu, v.y - mu, v.z - mu, v.w - mu);
    red[tid] = d.x * d.x + d.y * d.y + d.z * d.z + d.w * d.w;
    __syncthreads();
    for (int st = 128; st > 0; st >>= 1) {
        if (tid < st) red[tid] += red[tid + st];
        __syncthreads();
    }
    float rstd = rsqrtf(red[0] * (1.f / DM) + 1e-5f);
    float4 gg = *((const float4*)g + tid);
    float4 bbn = *((const float4*)b + tid);
    unsigned short o[4];
    o[0] = f2bf(d.x * rstd * gg.x + bbn.x);
    o[1] = f2bf(d.y * rstd * gg.y + bbn.y);
    o[2] = f2bf(d.z * rstd * gg.z + bbn.z);
    o[3] = f2bf(d.w * rstd * gg.w + bbn.w);
    *(ushort4*)(XN + (size_t)row * DM + tid * 4) = *(ushort4*)o;
}

// ---------------- weight convert+transpose: f32 [K][N] -> bf16 [N][K] ----------------
__global__ __launch_bounds__(256)
void convt_k(const float* __restrict__ src, unsigned short* __restrict__ dst,
             int K, int N)
{
    __shared__ __align__(16) unsigned short T[64][72];
    const int tid = threadIdx.x;
    const int n0 = blockIdx.x * 64, k0 = blockIdx.y * 64;
    const float* s = src + (size_t)blockIdx.z * K * N;
    unsigned short* d = dst + (size_t)blockIdx.z * K * N;
    #pragma unroll
    for (int q = 0; q < 4; ++q) {
        int f4 = tid + q * 256;
        int kk = f4 >> 4, nn = (f4 & 15) * 4;
        float4 v = *(const float4*)(s + (size_t)(k0 + kk) * N + n0 + nn);
        int swz = ((nn >> 2) & 7) << 3;
        T[nn + 0][kk ^ swz] = f2bf(v.x);
        T[nn + 1][kk ^ swz] = f2bf(v.y);
        T[nn + 2][kk ^ swz] = f2bf(v.z);
        T[nn + 3][kk ^ swz] = f2bf(v.w);
    }
    __syncthreads();
    #pragma unroll
    for (int q = 0; q < 2; ++q) {
        int s8 = tid + q * 256;
        int nn = s8 >> 3, kc = (s8 & 7) * 8;
        int swz = ((nn >> 2) & 7) << 3;
        *(short8*)(d + (size_t)(n0 + nn) * K + k0 + kc) =
            *(const short8*)&T[nn][kc ^ swz];
    }
}

// ======== shared GEMM body (ring-3, counted vmcnt, XOR swizzle) ========
#define GEMM_BODY(BM, BN)                                                        \
    constexpr int FRM = (BM) / 32;                                               \
    constexpr int FRN = (BN) / 32;                                               \
    constexpr int NIA = (BM) / 64;                                               \
    constexpr int NIB = (BN) / 64;                                               \
    constexpr int NLD = NIA + NIB;                                               \
    __shared__ __align__(16) unsigned short As[3][BM][32];                       \
    __shared__ __align__(16) unsigned short Bs[3][BN][32];                       \
    const int tid = threadIdx.x;                                                 \
    const int lane = tid & 63;                                                   \
    const int w = tid >> 6;                                                      \
    const int wr = w >> 1, wc = w & 1;                                           \
    const int l16 = lane & 15, g = lane >> 4;                                    \
    const int nby = M / (BM);                                                    \
    const int nwg = (N / (BN)) * nby;                                            \
    const int cpx = nwg >> 3;                                                    \
    const int bid = blockIdx.x;                                                  \
    const int sbid = (bid & 7) * cpx + (bid >> 3);                               \
    const int row0 = (sbid % nby) * (BM);                                        \
    const int col0 = (sbid / nby) * (BN);                                        \
    const int srowA = w * ((BM) / 4) + (lane >> 2);                              \
    const int srowB = w * ((BN) / 4) + (lane >> 2);                              \
    const int scol = (((lane & 3) ^ ((lane >> 3) & 3)) << 3);                    \
    const int rslot = ((g ^ ((l16 >> 1) & 3)) << 3);                             \
    const int ldst = (lane & 3) << 3;                                            \
    const unsigned short* ga = A  + (size_t)(row0 + srowA) * KS + (size_t)blockIdx.y * K + scol; \
    const unsigned short* gb = BT + (size_t)(col0 + srowB) * KS + (size_t)blockIdx.y * K + scol; \
    f32x4 acc[FRM][FRN] = {};                                                    \
    const int NT = K >> 5;                                                       \
    _Pragma("unroll")                                                            \
    for (int i = 0; i < NIA; ++i)                                                \
        gload_lds16(ga + (size_t)(i * 16) * KS, &As[0][srowA + i * 16][ldst]);   \
    _Pragma("unroll")                                                            \
    for (int i = 0; i < NIB; ++i)                                                \
        gload_lds16(gb + (size_t)(i * 16) * KS, &Bs[0][srowB + i * 16][ldst]);   \
    for (int t = 0; t < NT; ++t) {                                               \
        const int rb = t % 3;                                                    \
        if (t + 1 < NT) {                                                        \
            const int wb = (t + 1) % 3;                                          \
            const int ko = (t + 1) * 32;                                         \
            _Pragma("unroll")                                                    \
            for (int i = 0; i < NIA; ++i)                                        \
                gload_lds16(ga + ko + (size_t)(i * 16) * KS, &As[wb][srowA + i * 16][ldst]); \
            _Pragma("unroll")                                                    \
            for (int i = 0; i < NIB; ++i)                                        \
                gload_lds16(gb + ko + (size_t)(i * 16) * KS, &Bs[wb][srowB + i * 16][ldst]); \
            asm volatile("s_waitcnt vmcnt(%0)" :: "i"(NLD) : "memory");          \
        } else {                                                                 \
            asm volatile("s_waitcnt vmcnt(0)" ::: "memory");                     \
        }                                                                        \
        __builtin_amdgcn_s_barrier();                                            \
        short8 af[FRM], bf[FRN];                                                 \
        _Pragma("unroll")                                                        \
        for (int i = 0; i < FRM; ++i)                                            \
            af[i] = *(const short8*)&As[rb][wr * ((BM) / 2) + i * 16 + l16][rslot]; \
        _Pragma("unroll")                                                        \
        for (int j = 0; j < FRN; ++j)                                            \
            bf[j] = *(const short8*)&Bs[rb][wc * ((BN) / 2) + j * 16 + l16][rslot]; \
        __builtin_amdgcn_s_setprio(1);                                           \
        _Pragma("unroll")                                                        \
        for (int i = 0; i < FRM; ++i)                                            \
            _Pragma("unroll")                                                    \
            for (int j = 0; j < FRN; ++j)                                        \
                acc[i][j] = __builtin_amdgcn_mfma_f32_16x16x32_bf16(af[i], bf[j], acc[i][j], 0, 0, 0); \
        __builtin_amdgcn_s_setprio(0);                                           \
    }                                                                            \
    float* Cf = (float*)Cout + (size_t)blockIdx.y * M * N;                       \
    _Pragma("unroll")                                                            \
    for (int i = 0; i < FRM; ++i) {                                              \
        _Pragma("unroll")                                                        \
        for (int j = 0; j < FRN; ++j) {                                          \
            _Pragma("unroll")                                                    \
            for (int r = 0; r < 4; ++r) {                                        \
                int row = row0 + wr * ((BM) / 2) + i * 16 + g * 4 + r;           \
                int col = col0 + wc * ((BN) / 2) + j * 16 + l16;                 \
                float v = acc[i][j][r];                                          \
                if (bias)     v += bias[col];                                    \
                if (residual) v += residual[(size_t)row * N + col];              \
                if (relu)     v = fmaxf(v, 0.f);                                 \
                if (OUT_BF16) ((unsigned short*)Cout)[(size_t)row * N + col] = f2bf(v); \
                else          Cf[(size_t)row * N + col] = v;                     \
            }                                                                    \
        }                                                                        \
    }

// head GEMM: 128x128 tile (R12-proven)
template<bool OUT_BF16>
__global__ __launch_bounds__(256)
void gemm_big(const unsigned short* __restrict__ A, const unsigned short* __restrict__ BT,
              const float* __restrict__ bias, const float* __restrict__ residual,
              void* __restrict__ Cout, int M, int N, int K, int KS, int relu)
{
    GEMM_BODY(128, 128)
}

// layer GEMM: 128x64 tile (R13-proven, high occupancy)
template<bool OUT_BF16>
__global__ __launch_bounds__(256, 4)
void gemm_sm(const unsigned short* __restrict__ A, const unsigned short* __restrict__ BT,
             const float* __restrict__ bias, const float* __restrict__ residual,
             void* __restrict__ Cout, int M, int N, int K, int KS, int relu)
{
    GEMM_BODY(128, 64)
}

// ---------------- MFMA flash attention: KVBLK=128, 512 blocks (best: R14 config) ----------------
__global__ __launch_bounds__(256)
void attn_flash_k(const unsigned short* __restrict__ qkv, unsigned short* __restrict__ out)
{
    __shared__ unsigned short Ks[128][72];     // [kv][d]
    __shared__ unsigned short Vt[64][136];     // [d][kv]
    __shared__ unsigned short Ps[4][16][136];  // per-wave P [q][kv]

    const int tid = threadIdx.x;
    const int lane = tid & 63;
    const int w = tid >> 6;
    const int l16 = lane & 15, g = lane >> 4;

    const int id = blockIdx.x;
    const int qlow = id & 15;
    const int qb = (id < 256) ? (15 - qlow) : qlow;   // pair (i,i+256) sums to 15
    const int b = (id >> 4) & 1;
    const int h = id >> 5;

    const size_t rstr = 3 * DM;
    const unsigned short* base = qkv + (size_t)b * TSEQ * rstr + h * HDIM;

    const int krow = tid >> 1, kcol = (tid & 1) * 32;
    const int vkv = tid & 127, vdh = (tid >> 7) * 32;

    const int q0 = qb * 64;
    const int nt = (qb >> 1) + 1;

    const int qrow_w = q0 + w * 16 + l16;
    short8 aq0 = *(const short8*)(base + (size_t)qrow_w * rstr + g * 8);
    short8 aq1 = *(const short8*)(base + (size_t)qrow_w * rstr + 32 + g * 8);

    f32x4 acc_o[4] = {};
    float m_r[4] = {-INFINITY, -INFINITY, -INFINITY, -INFINITY};
    float l_r[4] = {};

    short8 kreg[4], vreg[4];
    {   // prologue: tile 0 -> regs
        const unsigned short* kb = base + (size_t)krow * rstr + DM + kcol;
        #pragma unroll
        for (int i = 0; i < 4; ++i) kreg[i] = *(const short8*)(kb + i * 8);
        const unsigned short* vb = base + (size_t)vkv * rstr + 2 * DM + vdh;
        #pragma unroll
        for (int i = 0; i < 4; ++i) vreg[i] = *(const short8*)(vb + i * 8);
    }

    for (int t = 0; t < nt; ++t) {
        #pragma unroll
        for (int i = 0; i < 4; ++i) *(short8*)&Ks[krow][kcol + i * 8] = kreg[i];
        #pragma unroll
        for (int jj = 0; jj < 4; ++jj)
            #pragma unroll
            for (int j = 0; j < 8; ++j)
                Vt[vdh + jj * 8 + j][vkv] = (unsigned short)vreg[jj][j];
        __syncthreads();

        if (t + 1 < nt) {   // next tile's loads in flight across compute
            const int kv0n = (t + 1) * 128;
            const unsigned short* kb = base + (size_t)(kv0n + krow) * rstr + DM + kcol;
            #pragma unroll
            for (int i = 0; i < 4; ++i) kreg[i] = *(const short8*)(kb + i * 8);
            const unsigned short* vb = base + (size_t)(kv0n + vkv) * rstr + 2 * DM + vdh;
            #pragma unroll
            for (int i = 0; i < 4; ++i) vreg[i] = *(const short8*)(vb + i * 8);
        }

        const int kv0 = t * 128;
        f32x4 acc_s[8] = {};
        #pragma unroll
        for (int ks = 0; ks < 8; ++ks) {
            short8 bk0 = *(const short8*)&Ks[ks * 16 + l16][g * 8];
            short8 bk1 = *(const short8*)&Ks[ks * 16 + l16][32 + g * 8];
            acc_s[ks] = __builtin_amdgcn_mfma_f32_16x16x32_bf16(aq0, bk0, acc_s[ks], 0, 0, 0);
            acc_s[ks] = __builtin_amdgcn_mfma_f32_16x16x32_bf16(aq1, bk1, acc_s[ks], 0, 0, 0);
        }
        const bool need_mask = (kv0 + 127 > q0 + w * 16);
        float alpha[4];
        #pragma unroll
        for (int r = 0; r < 4; ++r) {
            const int q_abs = q0 + w * 16 + g * 4 + r;
            float s[8];
            #pragma unroll
            for (int ks = 0; ks < 8; ++ks) {
                s[ks] = acc_s[ks][r] * 0.125f;
                if (need_mask && (kv0 + ks * 16 + l16 > q_abs)) s[ks] = -INFINITY;
            }
            float pm = fmaxf(fmaxf(fmaxf(s[0], s[1]), fmaxf(s[2], s[3])),
                             fmaxf(fmaxf(s[4], s[5]), fmaxf(s[6], s[7])));
            #pragma unroll
            for (int msk = 1; msk <= 8; msk <<= 1)
                pm = fmaxf(pm, __shfl_xor(pm, msk));
            // defer-max: only rescale when max grew by > 8 (T13)
            if (pm > m_r[r] + 8.f) { alpha[r] = __expf(m_r[r] - pm); m_r[r] = pm; }
            else                   { alpha[r] = 1.f; }
            float p[8], psum = 0.f;
            #pragma unroll
            for (int ks = 0; ks < 8; ++ks) {
                p[ks] = __expf(s[ks] - m_r[r]);   // masked: exp(-inf)=0
                psum += p[ks];
            }
            #pragma unroll
            for (int msk = 1; msk <= 8; msk <<= 1)
                psum += __shfl_xor(psum, msk);
            l_r[r] = l_r[r] * alpha[r] + psum;
            #pragma unroll
            for (int ks = 0; ks < 8; ++ks)
                Ps[w][g * 4 + r][ks * 16 + l16] = f2bf(p[ks]);
        }
        #pragma unroll
        for (int ds = 0; ds < 4; ++ds)
            #pragma unroll
            for (int r = 0; r < 4; ++r)
                acc_o[ds][r] *= alpha[r];
        short8 ap[4];
        #pragma unroll
        for (int kk = 0; kk < 4; ++kk)
            ap[kk] = *(const short8*)&Ps[w][l16][kk * 32 + g * 8];
        #pragma unroll
        for (int ds = 0; ds < 4; ++ds) {
            #pragma unroll
            for (int kk = 0; kk < 4; ++kk) {
                short8 bv = *(const short8*)&Vt[ds * 16 + l16][kk * 32 + g * 8];
                acc_o[ds] = __builtin_amdgcn_mfma_f32_16x16x32_bf16(ap[kk], bv, acc_o[ds], 0, 0, 0);
            }
        }
        __syncthreads();
    }

    #pragma unroll
    for (int ds = 0; ds < 4; ++ds)
        #pragma unroll
        for (int r = 0; r < 4; ++r) {
            int row = q0 + w * 16 + g * 4 + r;
            out[((size_t)b * TSEQ + row) * DM + h * HDIM + ds * 16 + l16] =
                f2bf(acc_o[ds][r] * (1.f / l_r[r]));
        }
}

// ---------------- orchestration ----------------
extern "C" void kernel_launch(void* const* d_in, const int* in_sizes, int n_in,
                              void* d_out, int out_size, void* d_ws, size_t ws_size,
                              hipStream_t stream)
{
    const int*   idx    = (const int*)  d_in[0];
    const float* embed  = (const float*)d_in[1];
    const float* Wqkv   = (const float*)d_in[2];
    const float* Wproj  = (const float*)d_in[3];
    const float* bproj  = (const float*)d_in[4];
    const float* ln1_g  = (const float*)d_in[5];
    const float* ln1_b  = (const float*)d_in[6];
    const float* ln2_g  = (const float*)d_in[7];
    const float* ln2_b  = (const float*)d_in[8];
    const float* W1     = (const float*)d_in[9];
    const float* b1     = (const float*)d_in[10];
    const float* W2     = (const float*)d_in[11];
    const float* b2     = (const float*)d_in[12];
    const float* lnf_g  = (const float*)d_in[13];
    const float* lnf_b  = (const float*)d_in[14];
    const float* Whead  = (const float*)d_in[15];
    float* out = (float*)d_out;

    float* X = (float*)d_ws;
    float* PK = X + (size_t)NROWS * DM;
    unsigned short* u = (unsigned short*)(PK + (size_t)4 * NROWS * DM);
    unsigned short* XN     = u;  u += (size_t)NROWS * DM;
    unsigned short* QKVb   = u;  u += (size_t)NROWS * 3 * DM;
    unsigned short* ATT    = u;  u += (size_t)NROWS * DM;
    unsigned short* FFH    = u;  u += (size_t)NROWS * DFFN;
    unsigned short* WqkvT  = u;  u += (size_t)NLAYER * 3 * DM * DM;
    unsigned short* WprojT = u;  u += (size_t)NLAYER * DM * DM;
    unsigned short* W1T    = u;  u += (size_t)NLAYER * DFFN * DM;
    unsigned short* W2T    = u;  u += (size_t)NLAYER * DM * DFFN;
    unsigned short* WheadT = u;  u += (size_t)NVOC * DM;

    convt_k<<<dim3(3 * DM / 64, DM / 64, NLAYER), 256, 0, stream>>>(Wqkv,  WqkvT,  DM,   3 * DM);
    convt_k<<<dim3(DM / 64,     DM / 64, NLAYER), 256, 0, stream>>>(Wproj, WprojT, DM,   DM);
    convt_k<<<dim3(DFFN / 64,   DM / 64, NLAYER), 256, 0, stream>>>(W1,    W1T,    DM,   DFFN);
    convt_k<<<dim3(DM / 64,   DFFN / 64, NLAYER), 256, 0, stream>>>(W2,    W2T,    DFFN, DM);
    convt_k<<<dim3(NVOC / 64,   DM / 64, 1),      256, 0, stream>>>(Whead, WheadT, DM,   NVOC);

    embed_pos_k<<<NROWS, 256, 0, stream>>>(idx, embed, X);
    layernorm_k<<<NROWS, 256, 0, stream>>>(X, ln1_g, ln1_b, XN);   // layer-0 ln1

    for (int l = 0; l < NLAYER; ++l) {
        const unsigned short* wqkvT_l  = WqkvT  + (size_t)l * 3 * DM * DM;
        const unsigned short* wprojT_l = WprojT + (size_t)l * DM * DM;
        const unsigned short* w1T_l    = W1T    + (size_t)l * DFFN * DM;
        const unsigned short* w2T_l    = W2T    + (size_t)l * DM * DFFN;
        const float* bproj_l = bproj + (size_t)l * DM;
        const float* b1_l = b1 + (size_t)l * DFFN;
        const float* b2_l = b2 + (size_t)l * DM;

        {   // qkv = ln1(x) @ Wqkv  (bf16 out): 768 blocks
            int nwg = (NROWS / 128) * (3 * DM / 64);
            gemm_sm<true><<<nwg, 256, 0, stream>>>(XN, wqkvT_l, nullptr, nullptr,
                                                   QKVb, NROWS, 3 * DM, DM, DM, 0);
        }
        {   // flash attention: 512 blocks, 2/CU, balanced qb pairs
            attn_flash_k<<<512, 256, 0, stream>>>(QKVb, ATT);
        }
        {   // proj: split-K=2 -> partials (512 blocks); fused reduce + ln2
            dim3 grid((NROWS / 128) * (DM / 64), 2);
            gemm_sm<false><<<grid, 256, 0, stream>>>(ATT, wprojT_l, nullptr, nullptr,
                                                     PK, NROWS, DM, 512, DM, 0);
            reduce_ln_k<<<NROWS, 256, 0, stream>>>(PK, 2, bproj_l, X,
                                                   ln2_g + (size_t)l * DM,
                                                   ln2_b + (size_t)l * DM, XN);
        }
        {   // ffh = relu(ln2 @ W1 + b1): 1024 blocks
            int nwg = (NROWS / 128) * (DFFN / 64);
            gemm_sm<true><<<nwg, 256, 0, stream>>>(XN, w1T_l, b1_l, nullptr,
                                                   FFH, NROWS, DFFN, DM, DM, 1);
        }
        {   // ffn2: split-K=4 -> partials (1024 blocks); reduce + ln1[l+1]/lnf
            dim3 grid((NROWS / 128) * (DM / 64), 4);
            gemm_sm<false><<<grid, 256, 0, stream>>>(FFH, w2T_l, nullptr, nullptr,
                                                     PK, NROWS, DM, 1024, DFFN, 0);
            const float* ng = (l + 1 < NLAYER) ? ln1_g + (size_t)(l + 1) * DM : lnf_g;
            const float* nb = (l + 1 < NLAYER) ? ln1_b + (size_t)(l + 1) * DM : lnf_b;
            reduce_ln_k<<<NROWS, 256, 0, stream>>>(PK, 4, b2_l, X, ng, nb, XN);
        }
    }

    {   // logits = lnf(x) @ Whead: 128^2 tile (R12-proven for HBM-streaming B)
        int nwg = (NROWS / 128) * (NVOC / 128);
        gemm_big<false><<<nwg, 256, 0, stream>>>(XN, WheadT, nullptr, nullptr,
                                                 out, NROWS, NVOC, DM, DM, 0);
    }
}